// Round 18
// baseline (111.805 us; speedup 1.0000x reference)
//
#include <hip/hip_runtime.h>
#include <hip/hip_bf16.h>
#include <math.h>

#define TT 100
#define NN 100
#define DD 1024
#define HH 8192
#define ILR 0.01f

typedef short bf16x8 __attribute__((ext_vector_type(8)));
typedef float f32x4 __attribute__((ext_vector_type(4)));

// Fragment-order layout (proven r8-r17): operand element (p,k) of a 16x32
// fragment at lane=((k>>3)&3)*16+p, elem=k&7. Frag block = 64 lanes x 16B.

__device__ __forceinline__ float wave_sum64(float v) {
#pragma unroll
  for (int off = 32; off; off >>= 1) v += __shfl_xor(v, off, 64);
  return v;
}

__device__ __forceinline__ unsigned short f2bf(float x) {
  __hip_bfloat16 b = __float2bfloat16(x);
  return *(unsigned short*)&b;
}
__device__ __forceinline__ float bf2f(unsigned short u) {
  __hip_bfloat16 b = *(__hip_bfloat16*)&u;
  return __bfloat162float(b);
}

// ---------------- K0: emit XA2f and XT2f (split-bf16, fragment order)
__global__ __launch_bounds__(256) void k0_frag(const float* __restrict__ xt,
                                               const float* __restrict__ xr,
                                               unsigned short* __restrict__ XA2f,
                                               unsigned short* __restrict__ XT2f) {
  const int tx = threadIdx.x & 31;   // m offset
  const int ty = threadIdx.x >> 5;   // r offset 0..7
  const int m0 = blockIdx.x * 32;
  const int r0 = blockIdx.y * 32;
#pragma unroll
  for (int i = 0; i < 4; i++) {
    const int r = r0 + ty + i * 8;   // 0..255
    const int m = m0 + tx;           // 0..1023
    float v = 0.f;
    if (r < 200) {
      const float* src = (r < TT) ? (xt + r * DD) : (xr + (r - TT) * DD);
      v = src[m];
    }
    const unsigned short h = f2bf(v);
    const unsigned short l = f2bf(v - bf2f(h));
    {  // XA2f: row=r, k=m
      const int idx = ((((r >> 4) * 32 + (m >> 5)) * 64) +
                       ((m >> 3) & 3) * 16 + (r & 15)) * 8 + (m & 7);
      XA2f[idx] = h;
      XA2f[idx + 262144] = l;
    }
    {  // XT2f: row=m, k=r
      const int idx = ((((m >> 4) * 8 + (r >> 5)) * 64) +
                       ((r >> 3) & 3) * 16 + (m & 15)) * 8 + (r & 7);
      XT2f[idx] = h;
      XT2f[idx + 262144] = l;
    }
  }
}

// ---------------- K1: Hall = tanh(X @ W + b), split-bf16 MFMA, full K/block.
// Grid 1024 (XCD-swizzled), 4 waves (2x2), wave = 32r x 16c, 32-col tile,
// K=1024 (16 chunks of 64k), 16KB LDS double-buffer, 1-deep prefetch
// (r16-proven best), fused bias+tanh epilogue.
__global__ __launch_bounds__(256, 4) void k1_mfma7(const unsigned short* __restrict__ XA2f,
                                                   const float* __restrict__ W,
                                                   const float* __restrict__ bias,
                                                   float* __restrict__ Hall) {
  __shared__ unsigned short Bsm[2 * 4096];  // [buf][h 2048 | l 2048] shorts
  const int tid = threadIdx.x;
  const int wid = tid >> 6;
  const int lane = tid & 63;
  const int flat = blockIdx.x;
  const int m8 = flat & 7;
  const int r_tile = (flat >> 3) & 3;
  const int chi = flat >> 5;             // 0..31
  const int c_tile = chi * 8 + m8;       // 0..255
  const int row0 = r_tile * 64;
  const int col0 = c_tile * 32;
  const int wr = wid >> 1;               // row half
  const int wc = wid & 1;                // col half (16 cols each)

  // staging: thread covers col sc, k-octet ko (8 k's)
  const int sc = tid & 31;
  const int ko = tid >> 5;               // 0..7
  const int sbase = (((sc >> 4) * 2 + (ko >> 2)) * 64 + (ko & 3) * 16 + (sc & 15)) * 8;

  f32x4 acc[2];
#pragma unroll
  for (int i = 0; i < 2; i++) {
    f32x4 zv = {0.f, 0.f, 0.f, 0.f};
    acc[i] = zv;
  }

  float wv[8];
#define K1_LOADW(CH)                                                           \
  _Pragma("unroll") for (int e = 0; e < 8; e++) wv[e] =                        \
      W[(size_t)((CH) * 64 + ko * 8 + e) * HH + col0 + sc];
#define K1_CVT(BUF)                                                            \
  {                                                                            \
    bf16x8 Hv, Lv;                                                             \
    _Pragma("unroll") for (int e = 0; e < 8; e++) {                            \
      const unsigned short hh = f2bf(wv[e]);                                   \
      Hv[e] = (short)hh;                                                       \
      Lv[e] = (short)f2bf(wv[e] - bf2f(hh));                                   \
    }                                                                          \
    unsigned short* d = Bsm + (BUF) * 4096 + sbase;                            \
    *(bf16x8*)d = Hv;                                                          \
    *(bf16x8*)(d + 2048) = Lv;                                                 \
  }
#define K1_MFMA(CHL, BUF)                                                      \
  _Pragma("unroll") for (int kb = 0; kb < 2; kb++) {                           \
    const int kbg = (CHL) * 2 + kb;                                            \
    bf16x8 ah[2], al[2], bh, bl;                                               \
    _Pragma("unroll") for (int mf = 0; mf < 2; mf++) {                         \
      const int tA = r_tile * 4 + wr * 2 + mf;                                 \
      const unsigned short* pa =                                               \
          XA2f + (size_t)((tA * 32 + kbg) * 64 + lane) * 8;                    \
      ah[mf] = *(const bf16x8*)pa;                                             \
      al[mf] = *(const bf16x8*)(pa + 262144);                                  \
    }                                                                          \
    {                                                                          \
      const unsigned short* pb =                                               \
          Bsm + (BUF) * 4096 + ((wc * 2 + kb) * 64 + lane) * 8;                \
      bh = *(const bf16x8*)pb;                                                 \
      bl = *(const bf16x8*)(pb + 2048);                                        \
    }                                                                          \
    _Pragma("unroll") for (int mf = 0; mf < 2; mf++) {                         \
      acc[mf] = __builtin_amdgcn_mfma_f32_16x16x32_bf16(ah[mf], bh, acc[mf], 0, 0, 0); \
      acc[mf] = __builtin_amdgcn_mfma_f32_16x16x32_bf16(ah[mf], bl, acc[mf], 0, 0, 0); \
      acc[mf] = __builtin_amdgcn_mfma_f32_16x16x32_bf16(al[mf], bh, acc[mf], 0, 0, 0); \
    }                                                                          \
  }

  K1_LOADW(0)
  K1_CVT(0)
  __syncthreads();

#pragma unroll 1
  for (int ch = 0; ch < 16; ch++) {
    if (ch < 15) { K1_LOADW(ch + 1) }
    K1_MFMA(ch, ch & 1)
    if (ch < 15) {
      K1_CVT((ch + 1) & 1)
      __syncthreads();
    }
  }
#undef K1_LOADW
#undef K1_CVT
#undef K1_MFMA

  // fused epilogue: bias + tanh + store; D layout col=lane&15, row=(lane>>4)*4+r
  const int l15 = lane & 15;
  const int drow = (lane >> 4) * 4;
#pragma unroll
  for (int mf = 0; mf < 2; mf++) {
    const int gr = row0 + wr * 32 + mf * 16 + drow;
    const int gc = col0 + wc * 16 + l15;
    const float bv = bias[gc];
#pragma unroll
    for (int r = 0; r < 4; r++) {
      const int row = gr + r;
      if (row < 200)
        Hall[(size_t)row * HH + gc] = tanhf(acc[mf][r] + bv);
    }
  }
}

// ---------------- K2a: split-K partial Gram (104 tasks x 16 K-slices)
__global__ __launch_bounds__(64) void k2a_gram(const float* __restrict__ Ht,
                                               const float* __restrict__ w0,
                                               float* __restrict__ Gp,
                                               float* __restrict__ y0p) {
  __shared__ float red[64 * 65];
  const int task = blockIdx.x;
  const int z = blockIdx.y;
  const int lane = threadIdx.x;
  const int kb = z * 512;
  if (task < 91) {
    int a = 0, rem = task;
    while (rem >= 13 - a) { rem -= 13 - a; a++; }
    const int b = a + rem;
    const float* Ra = Ht + (size_t)(a * 8) * HH + kb;
    const float* Rb = Ht + (size_t)(b * 8) * HH + kb;
    float acc[8][8];
#pragma unroll
    for (int r = 0; r < 8; r++)
#pragma unroll
      for (int c = 0; c < 8; c++) acc[r][c] = 0.f;
#pragma unroll
    for (int i = 0; i < 2; i++) {
      const int k = (lane + i * 64) * 4;
      float4 x[8];
#pragma unroll
      for (int r = 0; r < 8; r++) x[r] = *(const float4*)(Ra + (size_t)r * HH + k);
#pragma unroll
      for (int c = 0; c < 8; c++) {
        const float4 u = *(const float4*)(Rb + (size_t)c * HH + k);
#pragma unroll
        for (int r = 0; r < 8; r++) {
          acc[r][c] = fmaf(x[r].x, u.x, acc[r][c]);
          acc[r][c] = fmaf(x[r].y, u.y, acc[r][c]);
          acc[r][c] = fmaf(x[r].z, u.z, acc[r][c]);
          acc[r][c] = fmaf(x[r].w, u.w, acc[r][c]);
        }
      }
    }
#pragma unroll
    for (int r = 0; r < 8; r++)
#pragma unroll
      for (int c = 0; c < 8; c++) red[lane * 65 + r * 8 + c] = acc[r][c];
    __syncthreads();
    float s = 0.f;
#pragma unroll
    for (int i = 0; i < 64; i++) s += red[i * 65 + lane];
    Gp[(size_t)task * 1024 + z * 64 + lane] = s;
  } else {
    const int a = task - 91;
    const float* R = Ht + (size_t)(a * 8) * HH + kb;
    float acc[8] = {0.f, 0.f, 0.f, 0.f, 0.f, 0.f, 0.f, 0.f};
#pragma unroll
    for (int i = 0; i < 2; i++) {
      const int k = (lane + i * 64) * 4;
      const float4 wvv = *(const float4*)(w0 + kb + k);
#pragma unroll
      for (int r = 0; r < 8; r++) {
        const float4 x = *(const float4*)(R + (size_t)r * HH + k);
        acc[r] += x.x * wvv.x + x.y * wvv.y + x.z * wvv.z + x.w * wvv.w;
      }
    }
#pragma unroll
    for (int r = 0; r < 8; r++) acc[r] = wave_sum64(acc[r]);
    if (lane == 0) {
#pragma unroll
      for (int r = 0; r < 8; r++) y0p[a * 128 + z * 8 + r] = acc[r];
    }
  }
}

// ---------------- K3m: reduce Gp/y0p into LDS (same z-order as old k2b),
// then column-sweep forward substitution. 1 block x 256 thr.
__global__ __launch_bounds__(256) void k3_merged(const float* __restrict__ Gp,
                                                 const float* __restrict__ y0p,
                                                 const float* __restrict__ ytraj,
                                                 float* __restrict__ errT) {
  __shared__ float Gs[100 * 100];
  __shared__ float rhs[100];
  const int tid = threadIdx.x;
  for (int idx = tid; idx < 91 * 64; idx += 256) {
    const int task = idx >> 6;
    const int t = idx & 63;
    float s = 0.f;
#pragma unroll
    for (int z = 0; z < 16; z++) s += Gp[(size_t)task * 1024 + z * 64 + t];
    int a = 0, rem = task;
    while (rem >= 13 - a) { rem -= 13 - a; a++; }
    const int b = a + rem;
    const int gr = a * 8 + (t >> 3);
    const int gc = b * 8 + (t & 7);
    if (gr < 100 && gc < 100) {
      Gs[gr * 100 + gc] = s;
      Gs[gc * 100 + gr] = s;
    }
  }
  if (tid < 100) {
    float s = 0.f;
#pragma unroll
    for (int z = 0; z < 16; z++) s += y0p[(tid >> 3) * 128 + z * 8 + (tid & 7)];
    rhs[tid] = ytraj[tid] - s;
  }
  __syncthreads();
  if (tid >= 64) return;  // wave 0 solves
  const int l = tid;
  float acc_lo = 0.f, acc_hi = 0.f;
  float err_lo = 0.f, err_hi = 0.f;
#pragma unroll 4
  for (int t = 0; t < TT; t++) {
    const float a = (t < 64) ? __shfl(acc_lo, t) : __shfl(acc_hi, t - 64);
    const float err = rhs[t] - ILR * a;  // uniform across wave
    if (t < 64) {
      if (l == t) err_lo = err;
    } else {
      if (l == t - 64) err_hi = err;
    }
    const float g_lo = Gs[t * 100 + l];
    if (l > t) acc_lo = fmaf(err, g_lo, acc_lo);
    if (l < 36) {
      const float g_hi = Gs[t * 100 + 64 + l];
      if (64 + l > t) acc_hi = fmaf(err, g_hi, acc_hi);
    }
  }
  errT[l] = err_lo;
  if (l < 36) errT[64 + l] = err_hi;
}

// ---------------- K4a: per-chunk partials S_c = sum(e*h), P_c = prod(1-lr h^2)
__global__ __launch_bounds__(64) void k4a_scan(const float* __restrict__ Ht,
                                               const float* __restrict__ errT,
                                               float* __restrict__ Sp,
                                               float* __restrict__ Pp) {
  __shared__ float es[20];
  const int c = blockIdx.y;
  const int t0 = c * 20;
  if (threadIdx.x < 20) es[threadIdx.x] = errT[t0 + threadIdx.x];
  __syncthreads();
  const int j = blockIdx.x * 64 + threadIdx.x;
  float h[20];
#pragma unroll
  for (int u = 0; u < 20; u++) h[u] = Ht[(size_t)(t0 + u) * HH + j];
  float S = 0.f, P = 1.f;
#pragma unroll
  for (int u = 0; u < 20; u++) S += es[u] * h[u];
#pragma unroll
  for (int u = 0; u < 20; u++) P *= (1.f - ILR * h[u] * h[u]);
  Sp[(size_t)c * HH + j] = S;
  Pp[(size_t)c * HH + j] = P;
}

// ---------------- K4b: per-chunk final scan -> Ct, wf
__global__ __launch_bounds__(64) void k4b_emit(const float* __restrict__ Ht,
                                               const float* __restrict__ errT,
                                               const float* __restrict__ w0,
                                               const float* __restrict__ Sp,
                                               const float* __restrict__ Pp,
                                               float* __restrict__ Ct,
                                               float* __restrict__ wf) {
  __shared__ float es[20];
  const int c = blockIdx.y;
  const int t0 = c * 20;
  if (threadIdx.x < 20) es[threadIdx.x] = errT[t0 + threadIdx.x];
  __syncthreads();
  const int j = blockIdx.x * 64 + threadIdx.x;
  float Sv[5], Pv[5];
#pragma unroll
  for (int q = 0; q < 5; q++) {
    Sv[q] = Sp[(size_t)q * HH + j];
    Pv[q] = Pp[(size_t)q * HH + j];
  }
  float w = w0[j];
#pragma unroll
  for (int q = 0; q < 5; q++)
    if (q < c) w += ILR * Sv[q];
  float PA = 1.f;
#pragma unroll
  for (int q = 0; q < 5; q++)
    if (q > c) PA *= Pv[q];
  float h[20];
#pragma unroll
  for (int u = 0; u < 20; u++) h[u] = Ht[(size_t)(t0 + u) * HH + j];
  float ct[20];
#pragma unroll
  for (int u = 0; u < 20; u++) {
    const float e = es[u];
    w += ILR * e * h[u];
    ct[u] = ILR * (1.f - h[u] * h[u]) * (e - h[u] * w);
  }
  float r = PA;
#pragma unroll
  for (int u = 19; u >= 0; u--) {
    Ct[(size_t)(t0 + u) * HH + j] = ct[u] * r;
    r *= (1.f - ILR * h[u] * h[u]);
  }
  if (c == 4) wf[j] = w;
}

// ---------------- K5: e_i = Hrand[i]·w_f - y_rand[i]
__global__ __launch_bounds__(256) void k5_pred(const float* __restrict__ Hr,
                                               const float* __restrict__ wf,
                                               const float* __restrict__ yr,
                                               float* __restrict__ e_r) {
  const int i = blockIdx.x;
  const int tid = threadIdx.x;
  const float* row = Hr + (size_t)i * HH;
  float p = 0.f;
#pragma unroll
  for (int c = tid * 4; c < HH; c += 1024) {
    const float4 h4 = *(const float4*)(row + c);
    const float4 w4 = *(const float4*)(wf + c);
    p += h4.x * w4.x + h4.y * w4.y + h4.z * w4.z + h4.w * w4.w;
  }
  p = wave_sum64(p);
  __shared__ float ps[4];
  if ((tid & 63) == 0) ps[tid >> 6] = p;
  __syncthreads();
  if (tid == 0) {
    const float y = ps[0] + ps[1] + ps[2] + ps[3];
    e_r[i] = y - yr[i];
  }
}

// ---------------- K6a: v partials Vp[c][j]; block (0,0) also computes loss.
__global__ __launch_bounds__(64) void k6a_v(const float* __restrict__ Hr,
                                            const float* __restrict__ e_r,
                                            float* __restrict__ Vp,
                                            float* __restrict__ loss_out) {
  __shared__ float es[20];
  const int c = blockIdx.y;
  const int i0 = c * 20;
  if (threadIdx.x < 20) es[threadIdx.x] = e_r[i0 + threadIdx.x];
  __syncthreads();
  if (blockIdx.x == 0 && c == 0) {
    const int l = threadIdx.x;
    float s = e_r[l] * e_r[l];
    if (l < 36) {
      const float q = e_r[l + 64];
      s += q * q;
    }
    s = wave_sum64(s);
    if (l == 0) loss_out[0] = s / (float)NN;
  }
  const int j = blockIdx.x * 64 + threadIdx.x;
  float h[20];
#pragma unroll
  for (int u = 0; u < 20; u++) h[u] = Hr[(size_t)(i0 + u) * HH + j];
  float S = 0.f;
#pragma unroll
  for (int u = 0; u < 20; u++) S += es[u] * h[u];
  Vp[(size_t)c * HH + j] = S;
}

// ---------------- K6b: build MT2f rows (frag order, split bf16) + gb partials.
__global__ __launch_bounds__(256) void k6b_m(const float* __restrict__ Hr,
                                             const float* __restrict__ e_r,
                                             const float* __restrict__ wf,
                                             const float* __restrict__ Ct,
                                             const float* __restrict__ Vp,
                                             unsigned short* __restrict__ MT2f,
                                             float* __restrict__ gbp) {
  __shared__ float es[100];
  const int tid = threadIdx.x;
  for (int i = tid; i < 100; i += 256) es[i] = e_r[i];
  __syncthreads();
  const int j = blockIdx.x * 256 + tid;
  const int iMo = blockIdx.y;
  float v = 0.f;
#pragma unroll
  for (int c = 0; c < 5; c++) v += Vp[(size_t)c * HH + j];
  const float wfj = wf[j];
  float m[8];
#pragma unroll
  for (int e = 0; e < 8; e++) {
    const int iM = iMo * 8 + e;
    if (iM < 100) {
      m[e] = v * Ct[(size_t)iM * HH + j];
    } else if (iM < 200) {
      const float h = Hr[(size_t)(iM - 100) * HH + j];
      m[e] = es[iM - 100] * wfj * (1.f - h * h);
    } else {
      m[e] = 0.f;
    }
  }
  bf16x8 Hv, Lv;
  float gbs = 0.f;
#pragma unroll
  for (int e = 0; e < 8; e++) {
    const unsigned short hh = f2bf(m[e]);
    Hv[e] = (short)hh;
    Lv[e] = (short)f2bf(m[e] - bf2f(hh));
    gbs += m[e];
  }
  const int idx = (((j >> 4) * 8 + (iMo >> 2)) * 64 + (iMo & 3) * 16 + (j & 15)) * 8;
  *(bf16x8*)&MT2f[idx] = Hv;
  *(bf16x8*)&MT2f[idx + 2097152] = Lv;
  if (iMo < 25) gbp[(size_t)iMo * HH + j] = gbs;
}

// ---------------- K7: gW = Xall^T . M (split-bf16 MFMA) + gb reduce fold.
__global__ __launch_bounds__(256) void k7_mfma3(const unsigned short* __restrict__ XT2f,
                                                const unsigned short* __restrict__ MT2f,
                                                const float* __restrict__ gbp,
                                                float* __restrict__ gW,
                                                float* __restrict__ gb_out) {
  const int tid = threadIdx.x;
  if (blockIdx.x == 0 && tid < 128) {
    const int j = blockIdx.y * 128 + tid;
    float g = 0.f;
#pragma unroll
    for (int q = 0; q < 25; q++) g += gbp[(size_t)q * HH + j];
    gb_out[j] = g;
  }
  const int l = tid & 63;
  const int wid = tid >> 6;
  const int m0 = blockIdx.x * 128 + (wid >> 1) * 64;
  const int n0 = blockIdx.y * 128 + (wid & 1) * 64;
  const int tA0 = m0 >> 4;
  const int tN0 = n0 >> 4;

  f32x4 acc[4][4];
#pragma unroll
  for (int i = 0; i < 4; i++)
#pragma unroll
    for (int j = 0; j < 4; j++) {
      f32x4 z = {0.f, 0.f, 0.f, 0.f};
      acc[i][j] = z;
    }

#pragma unroll 2
  for (int kb = 0; kb < 8; kb++) {
    bf16x8 ah[4], al[4], bh[4], bl[4];
#pragma unroll
    for (int i = 0; i < 4; i++) {
      const unsigned short* pa = XT2f + (size_t)(((tA0 + i) * 8 + kb) * 64 + l) * 8;
      ah[i] = *(const bf16x8*)pa;
      al[i] = *(const bf16x8*)(pa + 262144);
      const unsigned short* pb = MT2f + (size_t)(((tN0 + i) * 8 + kb) * 64 + l) * 8;
      bh[i] = *(const bf16x8*)pb;
      bl[i] = *(const bf16x8*)(pb + 2097152);
    }
#pragma unroll
    for (int i = 0; i < 4; i++)
#pragma unroll
      for (int j = 0; j < 4; j++) {
        acc[i][j] = __builtin_amdgcn_mfma_f32_16x16x32_bf16(ah[i], bh[j], acc[i][j], 0, 0, 0);
        acc[i][j] = __builtin_amdgcn_mfma_f32_16x16x32_bf16(ah[i], bl[j], acc[i][j], 0, 0, 0);
        acc[i][j] = __builtin_amdgcn_mfma_f32_16x16x32_bf16(al[i], bh[j], acc[i][j], 0, 0, 0);
      }
  }
  const int l15 = l & 15;
  const int drow = (l >> 4) * 4;
#pragma unroll
  for (int i = 0; i < 4; i++)
#pragma unroll
    for (int j = 0; j < 4; j++) {
      float* dst = gW + (size_t)(m0 + i * 16 + drow) * HH + n0 + j * 16 + l15;
#pragma unroll
      for (int r = 0; r < 4; r++) dst[(size_t)r * HH] = acc[i][j][r];
    }
}

extern "C" void kernel_launch(void* const* d_in, const int* in_sizes, int n_in,
                              void* d_out, int out_size, void* d_ws, size_t ws_size,
                              hipStream_t stream) {
  (void)in_sizes; (void)n_in; (void)out_size; (void)ws_size;
  const float* xt = (const float*)d_in[0];   // [100,1024]
  const float* yt = (const float*)d_in[1];   // [100]
  const float* xr = (const float*)d_in[2];   // [100,1024]
  const float* yr = (const float*)d_in[3];   // [100]
  const float* W = (const float*)d_in[4];    // [1024,8192]
  const float* bias = (const float*)d_in[5]; // [8192]
  const float* w0 = (const float*)d_in[6];   // [8192]
  float* out = (float*)d_out;  // [0]=loss, [1..1+D*H)=gW, then gb[H]
  float* ws = (float*)d_ws;

  float* Hall = ws;                                 // 1,638,400 f
  float* Ht = Hall;
  float* Hr = Hall + TT * HH;
  unsigned short* XA2f = (unsigned short*)(Hall + 200 * HH);  // 524,288 sh
  unsigned short* XT2f = XA2f + 524288;                       // 524,288 sh
  float* scratch = (float*)(XT2f + 524288);
  float* Ct = scratch;                              // 819,200 f
  unsigned short* MT2f = (unsigned short*)(scratch + 819200);  // 4,194,304 sh
  float* Gp = scratch + 819200 + 2097152;           // 93,184 f
  float* y0p = Gp + 91 * 1024;                      // 1,664 f
  float* Sp = y0p + 13 * 128;                       // 40,960 f
  float* Pp = Sp + 5 * HH;                          // 40,960 f
  float* Vp = Pp + 5 * HH;                          // 40,960 f
  float* gbp = Vp + 5 * HH;                         // 204,800 f
  float* errT = gbp + 25 * HH;                      // 100 f
  float* e_r = errT + TT;                           // 100 f
  float* wf = e_r + NN;                             // 8,192 f

  k0_frag<<<dim3(32, 8), 256, 0, stream>>>(xt, xr, XA2f, XT2f);
  k1_mfma7<<<1024, 256, 0, stream>>>(XA2f, W, bias, Hall);
  k2a_gram<<<dim3(104, 16), 64, 0, stream>>>(Ht, w0, Gp, y0p);
  k3_merged<<<1, 256, 0, stream>>>(Gp, y0p, yt, errT);
  k4a_scan<<<dim3(128, 5), 64, 0, stream>>>(Ht, errT, Sp, Pp);
  k4b_emit<<<dim3(128, 5), 64, 0, stream>>>(Ht, errT, w0, Sp, Pp, Ct, wf);
  k5_pred<<<NN, 256, 0, stream>>>(Hr, wf, yr, e_r);
  k6a_v<<<dim3(128, 5), 64, 0, stream>>>(Hr, e_r, Vp, out);
  k6b_m<<<dim3(32, 32), 256, 0, stream>>>(Hr, e_r, wf, Ct, Vp, MT2f, gbp);
  k7_mfma3<<<dim3(8, 64), 256, 0, stream>>>(XT2f, MT2f, gbp, out + 1,
                                            out + 1 + (size_t)DD * HH);
}

// Round 19
// 105.437 us; speedup vs baseline: 1.0604x; 1.0604x over previous
//
#include <hip/hip_runtime.h>
#include <hip/hip_bf16.h>
#include <math.h>

#define TT 100
#define NN 100
#define DD 1024
#define HH 8192
#define ILR 0.01f

typedef short bf16x8 __attribute__((ext_vector_type(8)));
typedef float f32x4 __attribute__((ext_vector_type(4)));

// Fragment-order layout (proven r8-r18): operand element (p,k) of a 16x32
// fragment at lane=((k>>3)&3)*16+p, elem=k&7. Frag block = 64 lanes x 16B.

__device__ __forceinline__ float wave_sum64(float v) {
#pragma unroll
  for (int off = 32; off; off >>= 1) v += __shfl_xor(v, off, 64);
  return v;
}

__device__ __forceinline__ unsigned short f2bf(float x) {
  __hip_bfloat16 b = __float2bfloat16(x);
  return *(unsigned short*)&b;
}
__device__ __forceinline__ float bf2f(unsigned short u) {
  __hip_bfloat16 b = *(__hip_bfloat16*)&u;
  return __bfloat162float(b);
}

// ---------------- K0: emit XA2f and XT2f (split-bf16, fragment order)
__global__ __launch_bounds__(256) void k0_frag(const float* __restrict__ xt,
                                               const float* __restrict__ xr,
                                               unsigned short* __restrict__ XA2f,
                                               unsigned short* __restrict__ XT2f) {
  const int tx = threadIdx.x & 31;   // m offset
  const int ty = threadIdx.x >> 5;   // r offset 0..7
  const int m0 = blockIdx.x * 32;
  const int r0 = blockIdx.y * 32;
#pragma unroll
  for (int i = 0; i < 4; i++) {
    const int r = r0 + ty + i * 8;   // 0..255
    const int m = m0 + tx;           // 0..1023
    float v = 0.f;
    if (r < 200) {
      const float* src = (r < TT) ? (xt + r * DD) : (xr + (r - TT) * DD);
      v = src[m];
    }
    const unsigned short h = f2bf(v);
    const unsigned short l = f2bf(v - bf2f(h));
    {  // XA2f: row=r, k=m
      const int idx = ((((r >> 4) * 32 + (m >> 5)) * 64) +
                       ((m >> 3) & 3) * 16 + (r & 15)) * 8 + (m & 7);
      XA2f[idx] = h;
      XA2f[idx + 262144] = l;
    }
    {  // XT2f: row=m, k=r
      const int idx = ((((m >> 4) * 8 + (r >> 5)) * 64) +
                       ((r >> 3) & 3) * 16 + (m & 15)) * 8 + (r & 7);
      XT2f[idx] = h;
      XT2f[idx + 262144] = l;
    }
  }
}

// ---------------- K1: Hall = tanh(X @ W + b), split-bf16 MFMA, full K/block.
// Grid 1024 (XCD-swizzled), 4 waves (2x2), wave = 32r x 16c, 32-col tile,
// K=1024 (16 chunks of 64k), 16KB LDS double-buffer, 1-deep prefetch,
// fused bias+tanh epilogue. (r16-measured best)
__global__ __launch_bounds__(256, 4) void k1_mfma7(const unsigned short* __restrict__ XA2f,
                                                   const float* __restrict__ W,
                                                   const float* __restrict__ bias,
                                                   float* __restrict__ Hall) {
  __shared__ unsigned short Bsm[2 * 4096];  // [buf][h 2048 | l 2048] shorts
  const int tid = threadIdx.x;
  const int wid = tid >> 6;
  const int lane = tid & 63;
  const int flat = blockIdx.x;
  const int m8 = flat & 7;
  const int r_tile = (flat >> 3) & 3;
  const int chi = flat >> 5;             // 0..31
  const int c_tile = chi * 8 + m8;       // 0..255
  const int row0 = r_tile * 64;
  const int col0 = c_tile * 32;
  const int wr = wid >> 1;               // row half
  const int wc = wid & 1;                // col half (16 cols each)

  // staging: thread covers col sc, k-octet ko (8 k's)
  const int sc = tid & 31;
  const int ko = tid >> 5;               // 0..7
  const int sbase = (((sc >> 4) * 2 + (ko >> 2)) * 64 + (ko & 3) * 16 + (sc & 15)) * 8;

  f32x4 acc[2];
#pragma unroll
  for (int i = 0; i < 2; i++) {
    f32x4 zv = {0.f, 0.f, 0.f, 0.f};
    acc[i] = zv;
  }

  float wv[8];
#define K1_LOADW(CH)                                                           \
  _Pragma("unroll") for (int e = 0; e < 8; e++) wv[e] =                        \
      W[(size_t)((CH) * 64 + ko * 8 + e) * HH + col0 + sc];
#define K1_CVT(BUF)                                                            \
  {                                                                            \
    bf16x8 Hv, Lv;                                                             \
    _Pragma("unroll") for (int e = 0; e < 8; e++) {                            \
      const unsigned short hh = f2bf(wv[e]);                                   \
      Hv[e] = (short)hh;                                                       \
      Lv[e] = (short)f2bf(wv[e] - bf2f(hh));                                   \
    }                                                                          \
    unsigned short* d = Bsm + (BUF) * 4096 + sbase;                            \
    *(bf16x8*)d = Hv;                                                          \
    *(bf16x8*)(d + 2048) = Lv;                                                 \
  }
#define K1_MFMA(CHL, BUF)                                                      \
  _Pragma("unroll") for (int kb = 0; kb < 2; kb++) {                           \
    const int kbg = (CHL) * 2 + kb;                                            \
    bf16x8 ah[2], al[2], bh, bl;                                               \
    _Pragma("unroll") for (int mf = 0; mf < 2; mf++) {                         \
      const int tA = r_tile * 4 + wr * 2 + mf;                                 \
      const unsigned short* pa =                                               \
          XA2f + (size_t)((tA * 32 + kbg) * 64 + lane) * 8;                    \
      ah[mf] = *(const bf16x8*)pa;                                             \
      al[mf] = *(const bf16x8*)(pa + 262144);                                  \
    }                                                                          \
    {                                                                          \
      const unsigned short* pb =                                               \
          Bsm + (BUF) * 4096 + ((wc * 2 + kb) * 64 + lane) * 8;                \
      bh = *(const bf16x8*)pb;                                                 \
      bl = *(const bf16x8*)(pb + 2048);                                        \
    }                                                                          \
    _Pragma("unroll") for (int mf = 0; mf < 2; mf++) {                         \
      acc[mf] = __builtin_amdgcn_mfma_f32_16x16x32_bf16(ah[mf], bh, acc[mf], 0, 0, 0); \
      acc[mf] = __builtin_amdgcn_mfma_f32_16x16x32_bf16(ah[mf], bl, acc[mf], 0, 0, 0); \
      acc[mf] = __builtin_amdgcn_mfma_f32_16x16x32_bf16(al[mf], bh, acc[mf], 0, 0, 0); \
    }                                                                          \
  }

  K1_LOADW(0)
  K1_CVT(0)
  __syncthreads();

#pragma unroll 1
  for (int ch = 0; ch < 16; ch++) {
    if (ch < 15) { K1_LOADW(ch + 1) }
    K1_MFMA(ch, ch & 1)
    if (ch < 15) {
      K1_CVT((ch + 1) & 1)
      __syncthreads();
    }
  }
#undef K1_LOADW
#undef K1_CVT
#undef K1_MFMA

  // fused epilogue: bias + tanh + store; D layout col=lane&15, row=(lane>>4)*4+r
  const int l15 = lane & 15;
  const int drow = (lane >> 4) * 4;
#pragma unroll
  for (int mf = 0; mf < 2; mf++) {
    const int gr = row0 + wr * 32 + mf * 16 + drow;
    const int gc = col0 + wc * 16 + l15;
    const float bv = bias[gc];
#pragma unroll
    for (int r = 0; r < 4; r++) {
      const int row = gr + r;
      if (row < 200)
        Hall[(size_t)row * HH + gc] = tanhf(acc[mf][r] + bv);
    }
  }
}

// ---------------- K2a: split-K partial Gram (104 tasks x 16 K-slices)
__global__ __launch_bounds__(64) void k2a_gram(const float* __restrict__ Ht,
                                               const float* __restrict__ w0,
                                               float* __restrict__ Gp,
                                               float* __restrict__ y0p) {
  __shared__ float red[64 * 65];
  const int task = blockIdx.x;
  const int z = blockIdx.y;
  const int lane = threadIdx.x;
  const int kb = z * 512;
  if (task < 91) {
    int a = 0, rem = task;
    while (rem >= 13 - a) { rem -= 13 - a; a++; }
    const int b = a + rem;
    const float* Ra = Ht + (size_t)(a * 8) * HH + kb;
    const float* Rb = Ht + (size_t)(b * 8) * HH + kb;
    float acc[8][8];
#pragma unroll
    for (int r = 0; r < 8; r++)
#pragma unroll
      for (int c = 0; c < 8; c++) acc[r][c] = 0.f;
#pragma unroll
    for (int i = 0; i < 2; i++) {
      const int k = (lane + i * 64) * 4;
      float4 x[8];
#pragma unroll
      for (int r = 0; r < 8; r++) x[r] = *(const float4*)(Ra + (size_t)r * HH + k);
#pragma unroll
      for (int c = 0; c < 8; c++) {
        const float4 u = *(const float4*)(Rb + (size_t)c * HH + k);
#pragma unroll
        for (int r = 0; r < 8; r++) {
          acc[r][c] = fmaf(x[r].x, u.x, acc[r][c]);
          acc[r][c] = fmaf(x[r].y, u.y, acc[r][c]);
          acc[r][c] = fmaf(x[r].z, u.z, acc[r][c]);
          acc[r][c] = fmaf(x[r].w, u.w, acc[r][c]);
        }
      }
    }
#pragma unroll
    for (int r = 0; r < 8; r++)
#pragma unroll
      for (int c = 0; c < 8; c++) red[lane * 65 + r * 8 + c] = acc[r][c];
    __syncthreads();
    float s = 0.f;
#pragma unroll
    for (int i = 0; i < 64; i++) s += red[i * 65 + lane];
    Gp[(size_t)task * 1024 + z * 64 + lane] = s;
  } else {
    const int a = task - 91;
    const float* R = Ht + (size_t)(a * 8) * HH + kb;
    float acc[8] = {0.f, 0.f, 0.f, 0.f, 0.f, 0.f, 0.f, 0.f};
#pragma unroll
    for (int i = 0; i < 2; i++) {
      const int k = (lane + i * 64) * 4;
      const float4 wvv = *(const float4*)(w0 + kb + k);
#pragma unroll
      for (int r = 0; r < 8; r++) {
        const float4 x = *(const float4*)(R + (size_t)r * HH + k);
        acc[r] += x.x * wvv.x + x.y * wvv.y + x.z * wvv.z + x.w * wvv.w;
      }
    }
#pragma unroll
    for (int r = 0; r < 8; r++) acc[r] = wave_sum64(acc[r]);
    if (lane == 0) {
#pragma unroll
      for (int r = 0; r < 8; r++) y0p[a * 128 + z * 8 + r] = acc[r];
    }
  }
}

// ---------------- K2b: reduce partials -> G (symmetric) and y0.
__global__ __launch_bounds__(128) void k2b_reduce(const float* __restrict__ Gp,
                                                  const float* __restrict__ y0p,
                                                  float* __restrict__ G,
                                                  float* __restrict__ y0) {
  const int blk = blockIdx.x;
  const int t = threadIdx.x;
  if (blk < 91) {
    if (t < 64) {
      float s = 0.f;
#pragma unroll
      for (int z = 0; z < 16; z++) s += Gp[(size_t)blk * 1024 + z * 64 + t];
      int a = 0, rem = blk;
      while (rem >= 13 - a) { rem -= 13 - a; a++; }
      const int b = a + rem;
      const int gr = a * 8 + (t >> 3);
      const int gc = b * 8 + (t & 7);
      if (gr < 100 && gc < 100) {
        G[gr * 100 + gc] = s;
        G[gc * 100 + gr] = s;
      }
    }
  } else {
    if (t < 104) {
      float s = 0.f;
#pragma unroll
      for (int z = 0; z < 16; z++) s += y0p[(t >> 3) * 128 + z * 8 + (t & 7)];
      if (t < 100) y0[t] = s;
    }
  }
}

// ---------------- K3: column-sweep forward substitution (1 wave solves;
// 4 waves load).
__global__ __launch_bounds__(256) void k3_solve2(const float* __restrict__ G,
                                                 const float* __restrict__ y0,
                                                 const float* __restrict__ ytraj,
                                                 float* __restrict__ errT) {
  __shared__ float Gs[100 * 100];
  __shared__ float rhs[100];
  const int tid = threadIdx.x;
  for (int idx = tid; idx < 10000; idx += 256) Gs[idx] = G[idx];
  if (tid < 100) rhs[tid] = ytraj[tid] - y0[tid];
  __syncthreads();
  if (tid >= 64) return;  // wave 0 only
  const int l = tid;
  float acc_lo = 0.f, acc_hi = 0.f;
  float err_lo = 0.f, err_hi = 0.f;
#pragma unroll 4
  for (int t = 0; t < TT; t++) {
    const float a = (t < 64) ? __shfl(acc_lo, t) : __shfl(acc_hi, t - 64);
    const float err = rhs[t] - ILR * a;  // uniform across wave
    if (t < 64) {
      if (l == t) err_lo = err;
    } else {
      if (l == t - 64) err_hi = err;
    }
    const float g_lo = Gs[t * 100 + l];
    if (l > t) acc_lo = fmaf(err, g_lo, acc_lo);
    if (l < 36) {
      const float g_hi = Gs[t * 100 + 64 + l];
      if (64 + l > t) acc_hi = fmaf(err, g_hi, acc_hi);
    }
  }
  errT[l] = err_lo;
  if (l < 36) errT[64 + l] = err_hi;
}

// ---------------- K4a: per-chunk partials S_c = sum(e*h), P_c = prod(1-lr h^2)
__global__ __launch_bounds__(64) void k4a_scan(const float* __restrict__ Ht,
                                               const float* __restrict__ errT,
                                               float* __restrict__ Sp,
                                               float* __restrict__ Pp) {
  __shared__ float es[20];
  const int c = blockIdx.y;
  const int t0 = c * 20;
  if (threadIdx.x < 20) es[threadIdx.x] = errT[t0 + threadIdx.x];
  __syncthreads();
  const int j = blockIdx.x * 64 + threadIdx.x;
  float h[20];
#pragma unroll
  for (int u = 0; u < 20; u++) h[u] = Ht[(size_t)(t0 + u) * HH + j];
  float S = 0.f, P = 1.f;
#pragma unroll
  for (int u = 0; u < 20; u++) S += es[u] * h[u];
#pragma unroll
  for (int u = 0; u < 20; u++) P *= (1.f - ILR * h[u] * h[u]);
  Sp[(size_t)c * HH + j] = S;
  Pp[(size_t)c * HH + j] = P;
}

// ---------------- K4b: per-chunk final scan -> Ct, wf
__global__ __launch_bounds__(64) void k4b_emit(const float* __restrict__ Ht,
                                               const float* __restrict__ errT,
                                               const float* __restrict__ w0,
                                               const float* __restrict__ Sp,
                                               const float* __restrict__ Pp,
                                               float* __restrict__ Ct,
                                               float* __restrict__ wf) {
  __shared__ float es[20];
  const int c = blockIdx.y;
  const int t0 = c * 20;
  if (threadIdx.x < 20) es[threadIdx.x] = errT[t0 + threadIdx.x];
  __syncthreads();
  const int j = blockIdx.x * 64 + threadIdx.x;
  float Sv[5], Pv[5];
#pragma unroll
  for (int q = 0; q < 5; q++) {
    Sv[q] = Sp[(size_t)q * HH + j];
    Pv[q] = Pp[(size_t)q * HH + j];
  }
  float w = w0[j];
#pragma unroll
  for (int q = 0; q < 5; q++)
    if (q < c) w += ILR * Sv[q];
  float PA = 1.f;
#pragma unroll
  for (int q = 0; q < 5; q++)
    if (q > c) PA *= Pv[q];
  float h[20];
#pragma unroll
  for (int u = 0; u < 20; u++) h[u] = Ht[(size_t)(t0 + u) * HH + j];
  float ct[20];
#pragma unroll
  for (int u = 0; u < 20; u++) {
    const float e = es[u];
    w += ILR * e * h[u];
    ct[u] = ILR * (1.f - h[u] * h[u]) * (e - h[u] * w);
  }
  float r = PA;
#pragma unroll
  for (int u = 19; u >= 0; u--) {
    Ct[(size_t)(t0 + u) * HH + j] = ct[u] * r;
    r *= (1.f - ILR * h[u] * h[u]);
  }
  if (c == 4) wf[j] = w;
}

// ---------------- K5: e_i = Hrand[i]·w_f - y_rand[i]
__global__ __launch_bounds__(256) void k5_pred(const float* __restrict__ Hr,
                                               const float* __restrict__ wf,
                                               const float* __restrict__ yr,
                                               float* __restrict__ e_r) {
  const int i = blockIdx.x;
  const int tid = threadIdx.x;
  const float* row = Hr + (size_t)i * HH;
  float p = 0.f;
#pragma unroll
  for (int c = tid * 4; c < HH; c += 1024) {
    const float4 h4 = *(const float4*)(row + c);
    const float4 w4 = *(const float4*)(wf + c);
    p += h4.x * w4.x + h4.y * w4.y + h4.z * w4.z + h4.w * w4.w;
  }
  p = wave_sum64(p);
  __shared__ float ps[4];
  if ((tid & 63) == 0) ps[tid >> 6] = p;
  __syncthreads();
  if (tid == 0) {
    const float y = ps[0] + ps[1] + ps[2] + ps[3];
    e_r[i] = y - yr[i];
  }
}

// ---------------- K6a: v partials Vp[c][j]; block (0,0) also computes loss.
__global__ __launch_bounds__(64) void k6a_v(const float* __restrict__ Hr,
                                            const float* __restrict__ e_r,
                                            float* __restrict__ Vp,
                                            float* __restrict__ loss_out) {
  __shared__ float es[20];
  const int c = blockIdx.y;
  const int i0 = c * 20;
  if (threadIdx.x < 20) es[threadIdx.x] = e_r[i0 + threadIdx.x];
  __syncthreads();
  if (blockIdx.x == 0 && c == 0) {
    const int l = threadIdx.x;
    float s = e_r[l] * e_r[l];
    if (l < 36) {
      const float q = e_r[l + 64];
      s += q * q;
    }
    s = wave_sum64(s);
    if (l == 0) loss_out[0] = s / (float)NN;
  }
  const int j = blockIdx.x * 64 + threadIdx.x;
  float h[20];
#pragma unroll
  for (int u = 0; u < 20; u++) h[u] = Hr[(size_t)(i0 + u) * HH + j];
  float S = 0.f;
#pragma unroll
  for (int u = 0; u < 20; u++) S += es[u] * h[u];
  Vp[(size_t)c * HH + j] = S;
}

// ---------------- K6b: build MT2f rows (frag order, split bf16) + gb partials.
__global__ __launch_bounds__(256) void k6b_m(const float* __restrict__ Hr,
                                             const float* __restrict__ e_r,
                                             const float* __restrict__ wf,
                                             const float* __restrict__ Ct,
                                             const float* __restrict__ Vp,
                                             unsigned short* __restrict__ MT2f,
                                             float* __restrict__ gbp) {
  __shared__ float es[100];
  const int tid = threadIdx.x;
  for (int i = tid; i < 100; i += 256) es[i] = e_r[i];
  __syncthreads();
  const int j = blockIdx.x * 256 + tid;
  const int iMo = blockIdx.y;
  float v = 0.f;
#pragma unroll
  for (int c = 0; c < 5; c++) v += Vp[(size_t)c * HH + j];
  const float wfj = wf[j];
  float m[8];
#pragma unroll
  for (int e = 0; e < 8; e++) {
    const int iM = iMo * 8 + e;
    if (iM < 100) {
      m[e] = v * Ct[(size_t)iM * HH + j];
    } else if (iM < 200) {
      const float h = Hr[(size_t)(iM - 100) * HH + j];
      m[e] = es[iM - 100] * wfj * (1.f - h * h);
    } else {
      m[e] = 0.f;
    }
  }
  bf16x8 Hv, Lv;
  float gbs = 0.f;
#pragma unroll
  for (int e = 0; e < 8; e++) {
    const unsigned short hh = f2bf(m[e]);
    Hv[e] = (short)hh;
    Lv[e] = (short)f2bf(m[e] - bf2f(hh));
    gbs += m[e];
  }
  const int idx = (((j >> 4) * 8 + (iMo >> 2)) * 64 + (iMo & 3) * 16 + (j & 15)) * 8;
  *(bf16x8*)&MT2f[idx] = Hv;
  *(bf16x8*)&MT2f[idx + 2097152] = Lv;
  if (iMo < 25) gbp[(size_t)iMo * HH + j] = gbs;
}

// ---------------- K7: gW = Xall^T . M (split-bf16 MFMA) + gb reduce fold.
__global__ __launch_bounds__(256) void k7_mfma3(const unsigned short* __restrict__ XT2f,
                                                const unsigned short* __restrict__ MT2f,
                                                const float* __restrict__ gbp,
                                                float* __restrict__ gW,
                                                float* __restrict__ gb_out) {
  const int tid = threadIdx.x;
  if (blockIdx.x == 0 && tid < 128) {
    const int j = blockIdx.y * 128 + tid;
    float g = 0.f;
#pragma unroll
    for (int q = 0; q < 25; q++) g += gbp[(size_t)q * HH + j];
    gb_out[j] = g;
  }
  const int l = tid & 63;
  const int wid = tid >> 6;
  const int m0 = blockIdx.x * 128 + (wid >> 1) * 64;
  const int n0 = blockIdx.y * 128 + (wid & 1) * 64;
  const int tA0 = m0 >> 4;
  const int tN0 = n0 >> 4;

  f32x4 acc[4][4];
#pragma unroll
  for (int i = 0; i < 4; i++)
#pragma unroll
    for (int j = 0; j < 4; j++) {
      f32x4 z = {0.f, 0.f, 0.f, 0.f};
      acc[i][j] = z;
    }

#pragma unroll 2
  for (int kb = 0; kb < 8; kb++) {
    bf16x8 ah[4], al[4], bh[4], bl[4];
#pragma unroll
    for (int i = 0; i < 4; i++) {
      const unsigned short* pa = XT2f + (size_t)(((tA0 + i) * 8 + kb) * 64 + l) * 8;
      ah[i] = *(const bf16x8*)pa;
      al[i] = *(const bf16x8*)(pa + 262144);
      const unsigned short* pb = MT2f + (size_t)(((tN0 + i) * 8 + kb) * 64 + l) * 8;
      bh[i] = *(const bf16x8*)pb;
      bl[i] = *(const bf16x8*)(pb + 2097152);
    }
#pragma unroll
    for (int i = 0; i < 4; i++)
#pragma unroll
      for (int j = 0; j < 4; j++) {
        acc[i][j] = __builtin_amdgcn_mfma_f32_16x16x32_bf16(ah[i], bh[j], acc[i][j], 0, 0, 0);
        acc[i][j] = __builtin_amdgcn_mfma_f32_16x16x32_bf16(ah[i], bl[j], acc[i][j], 0, 0, 0);
        acc[i][j] = __builtin_amdgcn_mfma_f32_16x16x32_bf16(al[i], bh[j], acc[i][j], 0, 0, 0);
      }
  }
  const int l15 = l & 15;
  const int drow = (l >> 4) * 4;
#pragma unroll
  for (int i = 0; i < 4; i++)
#pragma unroll
    for (int j = 0; j < 4; j++) {
      float* dst = gW + (size_t)(m0 + i * 16 + drow) * HH + n0 + j * 16 + l15;
#pragma unroll
      for (int r = 0; r < 4; r++) dst[(size_t)r * HH] = acc[i][j][r];
    }
}

extern "C" void kernel_launch(void* const* d_in, const int* in_sizes, int n_in,
                              void* d_out, int out_size, void* d_ws, size_t ws_size,
                              hipStream_t stream) {
  (void)in_sizes; (void)n_in; (void)out_size; (void)ws_size;
  const float* xt = (const float*)d_in[0];   // [100,1024]
  const float* yt = (const float*)d_in[1];   // [100]
  const float* xr = (const float*)d_in[2];   // [100,1024]
  const float* yr = (const float*)d_in[3];   // [100]
  const float* W = (const float*)d_in[4];    // [1024,8192]
  const float* bias = (const float*)d_in[5]; // [8192]
  const float* w0 = (const float*)d_in[6];   // [8192]
  float* out = (float*)d_out;  // [0]=loss, [1..1+D*H)=gW, then gb[H]
  float* ws = (float*)d_ws;

  float* Hall = ws;                                 // 1,638,400 f
  float* Ht = Hall;
  float* Hr = Hall + TT * HH;
  unsigned short* XA2f = (unsigned short*)(Hall + 200 * HH);  // 524,288 sh
  unsigned short* XT2f = XA2f + 524288;                       // 524,288 sh
  float* scratch = (float*)(XT2f + 524288);
  float* Ct = scratch;                              // 819,200 f
  unsigned short* MT2f = (unsigned short*)(scratch + 819200);  // 4,194,304 sh
  float* Gp = scratch + 819200 + 2097152;           // 93,184 f
  float* y0p = Gp + 91 * 1024;                      // 1,664 f
  float* Sp = y0p + 13 * 128;                       // 40,960 f
  float* Pp = Sp + 5 * HH;                          // 40,960 f
  float* Vp = Pp + 5 * HH;                          // 40,960 f
  float* gbp = Vp + 5 * HH;                         // 204,800 f
  float* G = gbp + 25 * HH;                         // 10,000 f
  float* y0v = G + TT * TT;
  float* errT = y0v + TT;
  float* e_r = errT + TT;
  float* wf = e_r + NN;                             // 8,192 f

  k0_frag<<<dim3(32, 8), 256, 0, stream>>>(xt, xr, XA2f, XT2f);
  k1_mfma7<<<1024, 256, 0, stream>>>(XA2f, W, bias, Hall);
  k2a_gram<<<dim3(104, 16), 64, 0, stream>>>(Ht, w0, Gp, y0p);
  k2b_reduce<<<92, 128, 0, stream>>>(Gp, y0p, G, y0v);
  k3_solve2<<<1, 256, 0, stream>>>(G, y0v, yt, errT);
  k4a_scan<<<dim3(128, 5), 64, 0, stream>>>(Ht, errT, Sp, Pp);
  k4b_emit<<<dim3(128, 5), 64, 0, stream>>>(Ht, errT, w0, Sp, Pp, Ct, wf);
  k5_pred<<<NN, 256, 0, stream>>>(Hr, wf, yr, e_r);
  k6a_v<<<dim3(128, 5), 64, 0, stream>>>(Hr, e_r, Vp, out);
  k6b_m<<<dim3(32, 32), 256, 0, stream>>>(Hr, e_r, wf, Ct, Vp, MT2f, gbp);
  k7_mfma3<<<dim3(8, 64), 256, 0, stream>>>(XT2f, MT2f, gbp, out + 1,
                                            out + 1 + (size_t)DD * HH);
}